// Round 9
// baseline (113.299 us; speedup 1.0000x reference)
//
#include <hip/hip_runtime.h>
#include <math.h>

// Problem constants (fixed by the reference).
#define TOK   16
#define TOPA  2
#define NPAIR 32
#define DIM   1024
#define INTER 2816
#define NEXP  8

// Slot assignment for the fold-tree: after folding over lane bits 0..3
// (xor 1,2,4,8), lane L ends holding slot bitrev4(L&15). Choosing
// SLOT(j,m) = bitrev4(j + 8*m) makes pair j / matrix m land on lane j+8m.
#define SLOT(j, m) ((((j) & 1) << 3) | (((j) & 2) << 1) | (((j) & 4) >> 1) | (m))

__device__ __forceinline__ float dot4(float4 a, float4 b) {
    return a.x * b.x + a.y * b.y + a.z * b.z + a.w * b.w;
}

// Uniform 32-bit mask of pairs routed to expert e (scalar, lands in SGPRs).
__device__ __forceinline__ unsigned pair_mask(const int* __restrict__ eidx, int e) {
    unsigned mask = 0;
    #pragma unroll
    for (int k = 0; k < NPAIR / 4; ++k) {
        const int4 v = ((const int4*)eidx)[k];
        mask |= (unsigned)(v.x == e) << (4 * k + 0);
        mask |= (unsigned)(v.y == e) << (4 * k + 1);
        mask |= (unsigned)(v.z == e) << (4 * k + 2);
        mask |= (unsigned)(v.w == e) << (4 * k + 3);
    }
    return mask;
}

// ---------------------------------------------------------------------------
// Gate: h[p][o] = silu(x[t].w1[e][o]) * (x[t].w3[e][o])
// grid (176, 8): block owns 16 rows of w1+w3 for one expert; wave owns 4.
// Matched pairs' x rows staged once in LDS (32 KB). Per body (1 w1 row +
// 1 w3 row): 8 coalesced float4 loads, register double-buffered across
// bodies; 32 LDS b128 reads; 256 FMA; 18-shuffle fold-tree reduce.
// NO barriers in the row loop -> weight stream never drains.
// ---------------------------------------------------------------------------
__global__ __launch_bounds__(256, 4) void moe_gate_up(
    const float* __restrict__ x,  const int* __restrict__ eidx,
    const float* __restrict__ w1, const float* __restrict__ w3,
    float*       __restrict__ h)
{
    __shared__ float xs[8 * DIM];   // 32 KB: up to 8 pairs' x rows

    const int e = blockIdx.y;
    unsigned mrem = pair_mask(eidx, e);
    if (!mrem) return;   // this expert's weights are never read

    const int tid  = threadIdx.x;
    const int lane = tid & 63;
    const int wave = tid >> 6;
    const int r0   = blockIdx.x * 16;

    while (mrem) {
        // Extract up to 8 pairs (uniform; pad with pj[0], writes guarded).
        int pj[8];
        const int pfirst = __builtin_ctz(mrem);
        int npg = 0;
        #pragma unroll
        for (int j = 0; j < 8; ++j) {
            if (mrem) { pj[j] = __builtin_ctz(mrem); mrem &= mrem - 1; ++npg; }
            else      { pj[j] = pfirst; }
        }

        // Stage matched x rows into LDS. Static select of this thread's
        // pair (rule #20: no runtime index into a register array).
        const int srow = tid >> 5;          // 0..7: pair slot
        int sp = pj[0];
        #pragma unroll
        for (int j = 1; j < 8; ++j) if (srow == j) sp = pj[j];
        __syncthreads();   // previous group's readers are done
        {
            const int c0 = tid & 31;
            const float4* src = (const float4*)(x + (size_t)(sp >> 1) * DIM);
            float4* dst = (float4*)(xs + srow * DIM);
            #pragma unroll
            for (int jj = 0; jj < 8; ++jj)
                dst[c0 + 32 * jj] = src[c0 + 32 * jj];
        }
        __syncthreads();

        auto ldw = [&](float4 (&buf)[8], int m) {
            const int r = r0 + 4 * m + wave;
            const float4* a = (const float4*)(w1 + ((size_t)e * INTER + r) * DIM);
            const float4* b = (const float4*)(w3 + ((size_t)e * INTER + r) * DIM);
            #pragma unroll
            for (int k = 0; k < 4; ++k) {
                buf[k]     = a[k * 64 + lane];
                buf[4 + k] = b[k * 64 + lane];
            }
        };
        auto comp = [&](const float4 (&buf)[8], int m) {
            float acc[16];
            #pragma unroll
            for (int s = 0; s < 16; ++s) acc[s] = 0.f;
            #pragma unroll
            for (int k = 0; k < 4; ++k) {
                #pragma unroll
                for (int j = 0; j < 8; ++j) {
                    const float4 xv =
                        *(const float4*)(xs + j * DIM + (k * 64 + lane) * 4);
                    acc[SLOT(j, 0)] += dot4(buf[k],     xv);
                    acc[SLOT(j, 1)] += dot4(buf[4 + k], xv);
                }
            }
            // Fold-tree: 16 values -> 1 value/lane in 15 shuffles, then two
            // cross-group levels. Lane L ends with slot bitrev4(L&15).
            {
                const bool b0 = lane & 1;
                #pragma unroll
                for (int i = 0; i < 8; ++i) {
                    const float keep = b0 ? acc[i + 8] : acc[i];
                    const float send = b0 ? acc[i] : acc[i + 8];
                    acc[i] = keep + __shfl_xor(send, 1);
                }
                const bool b1 = lane & 2;
                #pragma unroll
                for (int i = 0; i < 4; ++i) {
                    const float keep = b1 ? acc[i + 4] : acc[i];
                    const float send = b1 ? acc[i] : acc[i + 4];
                    acc[i] = keep + __shfl_xor(send, 2);
                }
                const bool b2 = lane & 4;
                #pragma unroll
                for (int i = 0; i < 2; ++i) {
                    const float keep = b2 ? acc[i + 2] : acc[i];
                    const float send = b2 ? acc[i] : acc[i + 2];
                    acc[i] = keep + __shfl_xor(send, 4);
                }
                const bool b3 = lane & 8;
                {
                    const float keep = b3 ? acc[1] : acc[0];
                    const float send = b3 ? acc[0] : acc[1];
                    acc[0] = keep + __shfl_xor(send, 8);
                }
                acc[0] += __shfl_xor(acc[0], 16);
                acc[0] += __shfl_xor(acc[0], 32);
            }
            // Lane p (<8) holds s1[p]; lane p+8 holds s3[p]. Swap partners.
            const float part = __shfl_xor(acc[0], 8);
            if (lane < npg) {
                int pp = pj[0];
                #pragma unroll
                for (int j = 1; j < 8; ++j) if (lane == j) pp = pj[j];
                const float g = acc[0] / (1.f + __expf(-acc[0]));   // silu
                h[(size_t)pp * INTER + r0 + 4 * m + wave] = g * part;
            }
        };

        // 4 bodies, 2-deep register pipeline, no sync in the loop.
        float4 A[8], B[8];
        ldw(A, 0);
        ldw(B, 1); comp(A, 0);
        ldw(A, 2); comp(B, 1);
        ldw(B, 3); comp(A, 2);
        comp(B, 3);
    }
}

// ---------------------------------------------------------------------------
// Down (R4-proven, unchanged): out[p][d] = sum_o h[p][o] * w2[e][d][o]
// Wave owns 2 rows of w2 (11 float4/lane each), up to 4 pairs as
// accumulators, one 8-chain butterfly per wave body. grid (DIM/8, NEXP).
// h (360 KB) is L2-resident.
// ---------------------------------------------------------------------------
__global__ __launch_bounds__(256) void moe_down(
    const float* __restrict__ h,     // [NPAIR][INTER]
    const int*   __restrict__ eidx,  // [TOK][TOPA]
    const float* __restrict__ w2,    // [NEXP][DIM][INTER]
    float*       __restrict__ out)   // [NPAIR][DIM]
{
    const int e = blockIdx.y;
    unsigned mask = pair_mask(eidx, e);
    if (!mask) return;

    const int tid  = threadIdx.x;
    const int lane = tid & 63;
    const int wave = tid >> 6;
    const int r0   = blockIdx.x * 8 + wave * 2;

    const float4* w2r = (const float4*)(w2 + ((size_t)e * DIM + r0) * INTER);
    const float4* hb  = (const float4*)h;

    while (mask) {
        int p0 = __builtin_ctz(mask); mask &= mask - 1;
        int p1 = p0, p2 = p0, p3 = p0, nv = 1;
        if (mask) { p1 = __builtin_ctz(mask); mask &= mask - 1; nv = 2;
        if (mask) { p2 = __builtin_ctz(mask); mask &= mask - 1; nv = 3;
        if (mask) { p3 = __builtin_ctz(mask); mask &= mask - 1; nv = 4; } } }

        const float4* h0 = hb + (size_t)p0 * (INTER / 4);
        const float4* h1 = hb + (size_t)p1 * (INTER / 4);
        const float4* h2 = hb + (size_t)p2 * (INTER / 4);
        const float4* h3 = hb + (size_t)p3 * (INTER / 4);

        float s[2][4];
        #pragma unroll
        for (int r = 0; r < 2; ++r)
            #pragma unroll
            for (int j = 0; j < 4; ++j) s[r][j] = 0.f;

        #pragma unroll
        for (int k = 0; k < 11; ++k) {
            const float4 a0 = w2r[k * 64 + lane];
            const float4 a1 = w2r[704 + k * 64 + lane];   // row r0+1 (INTER/4 = 704)
            const float4 v0 = h0[k * 64 + lane];
            const float4 v1 = h1[k * 64 + lane];
            const float4 v2 = h2[k * 64 + lane];
            const float4 v3 = h3[k * 64 + lane];
            s[0][0] += dot4(a0, v0); s[0][1] += dot4(a0, v1);
            s[0][2] += dot4(a0, v2); s[0][3] += dot4(a0, v3);
            s[1][0] += dot4(a1, v0); s[1][1] += dot4(a1, v1);
            s[1][2] += dot4(a1, v2); s[1][3] += dot4(a1, v3);
        }

        #pragma unroll
        for (int off = 1; off < 64; off <<= 1) {
            #pragma unroll
            for (int r = 0; r < 2; ++r)
                #pragma unroll
                for (int j = 0; j < 4; ++j)
                    s[r][j] += __shfl_xor(s[r][j], off);
        }

        if (lane == 0) {
            const int pp[4] = { p0, p1, p2, p3 };
            #pragma unroll
            for (int j = 0; j < 4; ++j) {
                if (j < nv) {
                    #pragma unroll
                    for (int r = 0; r < 2; ++r)
                        out[(size_t)pp[j] * DIM + r0 + r] = s[r][j];
                }
            }
        }
    }
}

// ---------------------------------------------------------------------------
extern "C" void kernel_launch(void* const* d_in, const int* in_sizes, int n_in,
                              void* d_out, int out_size, void* d_ws, size_t ws_size,
                              hipStream_t stream) {
    const float* x    = (const float*)d_in[0];
    const int*   eidx = (const int*)  d_in[1];
    const float* w1   = (const float*)d_in[2];
    const float* w2   = (const float*)d_in[3];
    const float* w3   = (const float*)d_in[4];
    float* out = (float*)d_out;
    float* hws = (float*)d_ws;   // [NPAIR][INTER] f32 = 360448 B

    dim3 g1(INTER / 16, NEXP);   // (176, 8): 16 rows/block, 4 rows/wave
    moe_gate_up<<<g1, 256, 0, stream>>>(x, eidx, w1, w3, hws);

    dim3 g2(DIM / 8, NEXP);      // (128, 8): 2 rows/wave
    moe_down<<<g2, 256, 0, stream>>>(hws, eidx, w2, out);
}

// Round 10
// 64.940 us; speedup vs baseline: 1.7447x; 1.7447x over previous
//
#include <hip/hip_runtime.h>
#include <math.h>

// Problem constants (fixed by the reference).
#define TOK   16
#define TOPA  2
#define NPAIR 32
#define DIM   1024
#define INTER 2816
#define NEXP  8

__device__ __forceinline__ float dot4(float4 a, float4 b) {
    return a.x * b.x + a.y * b.y + a.z * b.z + a.w * b.w;
}

// VALU-pipe wave reduction via DPP (no DS ops). Result valid in lane 63.
// row_shr:{1,2,4,8} build per-16-row prefix sums; row_bcast:15/31 cross rows.
// update_dpp(old=0,...): lanes with no valid source read 0.
#define DPP_ADD(x, ctrl, rm)                                              \
    ((x) + __int_as_float(__builtin_amdgcn_update_dpp(                    \
         0, __float_as_int(x), (ctrl), (rm), 0xf, false)))

__device__ __forceinline__ float dpp_wave_sum(float x) {
    x = DPP_ADD(x, 0x111, 0xf);   // row_shr:1
    x = DPP_ADD(x, 0x112, 0xf);   // row_shr:2
    x = DPP_ADD(x, 0x114, 0xf);   // row_shr:4
    x = DPP_ADD(x, 0x118, 0xf);   // row_shr:8  -> lane 15+16k = row sum
    x = DPP_ADD(x, 0x142, 0xa);   // row_bcast:15 -> lane 31/63 accumulate
    x = DPP_ADD(x, 0x143, 0xc);   // row_bcast:31 -> lane 63 = full sum
    return x;
}

// Uniform 32-bit mask of pairs routed to expert e (lands in SGPRs).
__device__ __forceinline__ unsigned pair_mask(const int* __restrict__ eidx, int e) {
    unsigned mask = 0;
    #pragma unroll
    for (int k = 0; k < NPAIR / 4; ++k) {
        const int4 v = ((const int4*)eidx)[k];
        mask |= (unsigned)(v.x == e) << (4 * k + 0);
        mask |= (unsigned)(v.y == e) << (4 * k + 1);
        mask |= (unsigned)(v.z == e) << (4 * k + 2);
        mask |= (unsigned)(v.w == e) << (4 * k + 3);
    }
    return mask;
}

// ---------------------------------------------------------------------------
// Kernel 1 (R4 structure, DPP reduction): wave owns 2 rows of w1 + 2 of w3,
// coalesced row[k*64+lane] float4 loads (1 KB/instr), up to 4 pairs as
// k-loop accumulators, x read from L2. Reduction: 16 independent DPP chains
// on the VALU pipe (zero DS ops, zero barriers). grid (INTER/8, NEXP).
// ---------------------------------------------------------------------------
__global__ __launch_bounds__(256) void moe_gate_up(
    const float* __restrict__ x,     // [TOK][DIM]
    const int*   __restrict__ eidx,  // [TOK][TOPA]
    const float* __restrict__ w1,    // [NEXP][INTER][DIM]
    const float* __restrict__ w3,    // [NEXP][INTER][DIM]
    float*       __restrict__ h)     // [NPAIR][INTER]
{
    const int e = blockIdx.y;
    unsigned mask = pair_mask(eidx, e);
    if (!mask) return;   // skip this expert's weights entirely

    const int tid  = threadIdx.x;
    const int lane = tid & 63;
    const int wave = tid >> 6;
    const int r0   = blockIdx.x * 8 + wave * 2;

    const float4* w1r = (const float4*)(w1 + ((size_t)e * INTER + r0) * DIM);
    const float4* w3r = (const float4*)(w3 + ((size_t)e * INTER + r0) * DIM);
    const float4* xb  = (const float4*)x;

    while (mask) {
        // Pull up to 4 pairs (pad with duplicates of p0; writes guarded by nv).
        int p0 = __builtin_ctz(mask); mask &= mask - 1;
        int p1 = p0, p2 = p0, p3 = p0, nv = 1;
        if (mask) { p1 = __builtin_ctz(mask); mask &= mask - 1; nv = 2;
        if (mask) { p2 = __builtin_ctz(mask); mask &= mask - 1; nv = 3;
        if (mask) { p3 = __builtin_ctz(mask); mask &= mask - 1; nv = 4; } } }

        const float4* x0 = xb + (size_t)(p0 >> 1) * (DIM / 4);
        const float4* x1 = xb + (size_t)(p1 >> 1) * (DIM / 4);
        const float4* x2 = xb + (size_t)(p2 >> 1) * (DIM / 4);
        const float4* x3 = xb + (size_t)(p3 >> 1) * (DIM / 4);

        float s1[2][4], s3[2][4];
        #pragma unroll
        for (int r = 0; r < 2; ++r)
            #pragma unroll
            for (int j = 0; j < 4; ++j) { s1[r][j] = 0.f; s3[r][j] = 0.f; }

        #pragma unroll
        for (int k = 0; k < 4; ++k) {
            const float4 a0 = w1r[k * 64 + lane];
            const float4 a1 = w1r[256 + k * 64 + lane];   // row r0+1
            const float4 b0 = w3r[k * 64 + lane];
            const float4 b1 = w3r[256 + k * 64 + lane];
            const float4 v0 = x0[k * 64 + lane];
            const float4 v1 = x1[k * 64 + lane];
            const float4 v2 = x2[k * 64 + lane];
            const float4 v3 = x3[k * 64 + lane];
            s1[0][0] += dot4(a0, v0); s1[0][1] += dot4(a0, v1);
            s1[0][2] += dot4(a0, v2); s1[0][3] += dot4(a0, v3);
            s1[1][0] += dot4(a1, v0); s1[1][1] += dot4(a1, v1);
            s1[1][2] += dot4(a1, v2); s1[1][3] += dot4(a1, v3);
            s3[0][0] += dot4(b0, v0); s3[0][1] += dot4(b0, v1);
            s3[0][2] += dot4(b0, v2); s3[0][3] += dot4(b0, v3);
            s3[1][0] += dot4(b1, v0); s3[1][1] += dot4(b1, v1);
            s3[1][2] += dot4(b1, v2); s3[1][3] += dot4(b1, v3);
        }

        // 16 independent VALU DPP-reduction chains (no DS pipe, no barriers).
        #pragma unroll
        for (int r = 0; r < 2; ++r)
            #pragma unroll
            for (int j = 0; j < 4; ++j) {
                s1[r][j] = dpp_wave_sum(s1[r][j]);
                s3[r][j] = dpp_wave_sum(s3[r][j]);
            }

        if (lane == 63) {
            const int pp[4] = { p0, p1, p2, p3 };
            #pragma unroll
            for (int j = 0; j < 4; ++j) {
                if (j < nv) {
                    #pragma unroll
                    for (int r = 0; r < 2; ++r) {
                        const float g = s1[r][j] / (1.f + __expf(-s1[r][j]));
                        h[(size_t)pp[j] * INTER + r0 + r] = g * s3[r][j];
                    }
                }
            }
        }
    }
}

// ---------------------------------------------------------------------------
// Kernel 2 (R4 structure, DPP reduction): wave owns 2 rows of w2
// (11 float4/lane each), up to 4 pairs as accumulators. grid (DIM/8, NEXP).
// h (360 KB) is L2-resident.
// ---------------------------------------------------------------------------
__global__ __launch_bounds__(256) void moe_down(
    const float* __restrict__ h,     // [NPAIR][INTER]
    const int*   __restrict__ eidx,  // [TOK][TOPA]
    const float* __restrict__ w2,    // [NEXP][DIM][INTER]
    float*       __restrict__ out)   // [NPAIR][DIM]
{
    const int e = blockIdx.y;
    unsigned mask = pair_mask(eidx, e);
    if (!mask) return;

    const int tid  = threadIdx.x;
    const int lane = tid & 63;
    const int wave = tid >> 6;
    const int r0   = blockIdx.x * 8 + wave * 2;

    const float4* w2r = (const float4*)(w2 + ((size_t)e * DIM + r0) * INTER);
    const float4* hb  = (const float4*)h;

    while (mask) {
        int p0 = __builtin_ctz(mask); mask &= mask - 1;
        int p1 = p0, p2 = p0, p3 = p0, nv = 1;
        if (mask) { p1 = __builtin_ctz(mask); mask &= mask - 1; nv = 2;
        if (mask) { p2 = __builtin_ctz(mask); mask &= mask - 1; nv = 3;
        if (mask) { p3 = __builtin_ctz(mask); mask &= mask - 1; nv = 4; } } }

        const float4* h0 = hb + (size_t)p0 * (INTER / 4);
        const float4* h1 = hb + (size_t)p1 * (INTER / 4);
        const float4* h2 = hb + (size_t)p2 * (INTER / 4);
        const float4* h3 = hb + (size_t)p3 * (INTER / 4);

        float s[2][4];
        #pragma unroll
        for (int r = 0; r < 2; ++r)
            #pragma unroll
            for (int j = 0; j < 4; ++j) s[r][j] = 0.f;

        #pragma unroll
        for (int k = 0; k < 11; ++k) {
            const float4 a0 = w2r[k * 64 + lane];
            const float4 a1 = w2r[704 + k * 64 + lane];   // row r0+1 (INTER/4 = 704)
            const float4 v0 = h0[k * 64 + lane];
            const float4 v1 = h1[k * 64 + lane];
            const float4 v2 = h2[k * 64 + lane];
            const float4 v3 = h3[k * 64 + lane];
            s[0][0] += dot4(a0, v0); s[0][1] += dot4(a0, v1);
            s[0][2] += dot4(a0, v2); s[0][3] += dot4(a0, v3);
            s[1][0] += dot4(a1, v0); s[1][1] += dot4(a1, v1);
            s[1][2] += dot4(a1, v2); s[1][3] += dot4(a1, v3);
        }

        // 8 independent VALU DPP-reduction chains.
        #pragma unroll
        for (int r = 0; r < 2; ++r)
            #pragma unroll
            for (int j = 0; j < 4; ++j)
                s[r][j] = dpp_wave_sum(s[r][j]);

        if (lane == 63) {
            const int pp[4] = { p0, p1, p2, p3 };
            #pragma unroll
            for (int j = 0; j < 4; ++j) {
                if (j < nv) {
                    #pragma unroll
                    for (int r = 0; r < 2; ++r)
                        out[(size_t)pp[j] * DIM + r0 + r] = s[r][j];
                }
            }
        }
    }
}

// ---------------------------------------------------------------------------
extern "C" void kernel_launch(void* const* d_in, const int* in_sizes, int n_in,
                              void* d_out, int out_size, void* d_ws, size_t ws_size,
                              hipStream_t stream) {
    const float* x    = (const float*)d_in[0];
    const int*   eidx = (const int*)  d_in[1];
    const float* w1   = (const float*)d_in[2];
    const float* w2   = (const float*)d_in[3];
    const float* w3   = (const float*)d_in[4];
    float* out = (float*)d_out;
    float* hws = (float*)d_ws;   // [NPAIR][INTER] f32 = 360448 B

    dim3 g1(INTER / 8, NEXP);   // 352 x 8 blocks, 2 rows/wave
    moe_gate_up<<<g1, 256, 0, stream>>>(x, eidx, w1, w3, hws);

    dim3 g2(DIM / 8, NEXP);     // 128 x 8 blocks, 2 rows/wave
    moe_down<<<g2, 256, 0, stream>>>(hws, eidx, w2, out);
}